// Round 12
// baseline (102.081 us; speedup 1.0000x reference)
//
#include <hip/hip_runtime.h>
#include <stdint.h>

// InterGate: B=1, C=192, H=W=96.  Flash-attention formulation:
//   Q = (latent*w4)^T, K = refined^T, V = (latent*w4)^T   (all [9216, 192])
//   out = refined*w5 + (softmax(Q K^T) V)^T
// Round-12: 64 q/wave at 1 wave/SIMD.  r7-r11 proved the 32q/wave structure
// is pinned at ~73us by per-wave LDS traffic (24KB/32-key tile) + phase
// serialization.  Total LDS volume scales as 1/(q per wave); registers
// allow 64q only at 1 wave/SIMD (~400 VGPR) -- where each wave OWNS its
// SIMD's MFMA pipe, so single-wave pipe mixing replaces the TLP we give up.
//   * 2 waves x 64q per block (128q), grid 72 x KS=7 -> ~2 blocks/CU,
//     4 waves/CU, one per SIMD
//   * 32-key K|V tiles triple-buffered (72KB), staged 2 ahead,
//     counted s_waitcnt vmcnt(12) + raw s_barrier (2-wave, cheap)
//   * each K/V fragment read feeds 2 MFMAs (qa/qb, OA/OB subtiles)
//   * -M0L folded into BOTH S chain inits -> p = exp2(S) directly
//   * f16 single-term swapped QK, no-max softmax, permuted-V rows
//     (P B-frag = cvt_pk words, zero cross-lane moves)  [validated r3-r11]

#define NQ 9216
#define NC 192
#define FR 1769472      // 9216*192 elements per fragment array
#define LOG2E 1.4426950408889634f
#define M0L 36.06737602f   // 25 * log2(e)

typedef short    bfrag  __attribute__((ext_vector_type(8)));   // 8 bf16
typedef _Float16 hfrag  __attribute__((ext_vector_type(8)));   // 8 f16
typedef short    sfrag4 __attribute__((ext_vector_type(4)));   // 4 bf16 (8B)
typedef float    facc16 __attribute__((ext_vector_type(16)));  // 32x32 accum
typedef int      ifrag4 __attribute__((ext_vector_type(4)));

__device__ __forceinline__ short f2bf(float x) {
    uint32_t u = __builtin_bit_cast(uint32_t, x);
    u = (u + 0x7fffu + ((u >> 16) & 1u)) >> 16;
    return (short)u;
}
__device__ __forceinline__ float bf2f(short s) {
    uint32_t u = ((uint32_t)(uint16_t)s) << 16;
    return __builtin_bit_cast(float, u);
}
__device__ __forceinline__ int cvtpk_bf16(float lo, float hi) {
    int r;
    asm("v_cvt_pk_bf16_f32 %0, %1, %2" : "=v"(r) : "v"(lo), "v"(hi));
    return r;
}
__device__ __forceinline__ float exp2_raw(float x) {   // 2^x via v_exp_f32
    float r;
    asm("v_exp_f32 %0, %1" : "=v"(r) : "v"(x));
    return r;
}
__device__ __forceinline__ void gload_lds16(const void* g, void* l) {
    __builtin_amdgcn_global_load_lds(
        (__attribute__((address_space(1))) const void*)(uintptr_t)g,
        (__attribute__((address_space(3))) void*)(uint32_t)(uintptr_t)l,
        16, 0, 0);
}

// ---------------------------------------------------------------------------
// Prep: fragment-ordered arrays for 32x32x16 (l32=lane&31, h=lane>>5).
// Qf (f16, B-frag, pre-scaled by log2e):
//   [qw(288)][t(12)][lane][i8] = log2e * Q[qw*32+l32][t*16+h*8+i]
// KV per 32-key group g (12288 shorts = 24KB), 288 groups:
//  [0]    K (f16, A-frag): [t(12)][lane][i8] = K[g*32+l32][t*16+h*8+i]
//  [6144] V (bf16, A-frag of V^T, PERMUTED key rows matching S' C/D order):
//         [T(2)][cb(6)][lane][i8] = V[g*32+T*16+(i&3)+8*(i>>2)+4*h][cb*32+l32]
// ---------------------------------------------------------------------------
__global__ __launch_bounds__(256) void InterGate_prep(
    const float* __restrict__ latent, const float* __restrict__ refined,
    const float* __restrict__ w4,
    short* __restrict__ Qf, short* __restrict__ KV)
{
    const int wid  = blockIdx.x * 4 + (threadIdx.x >> 6);
    const int lane = threadIdx.x & 63;
    const int l32  = lane & 31, h = lane >> 5;

    if (wid < 3456) {                       // Q fragments (latent*w4*log2e), f16
        const int qw = wid / 12, t = wid % 12;
        const int q  = qw * 32 + l32;
        const int c0 = t * 16 + h * 8;
        hfrag hv;
        #pragma unroll
        for (int i = 0; i < 8; i++) {
            size_t idx = (size_t)(c0 + i) * NQ + q;
            hv[i] = (_Float16)(latent[idx] * w4[idx] * LOG2E);
        }
        *(hfrag*)(void*)(Qf + ((size_t)wid * 64 + lane) * 8) = hv;
    } else if (wid < 6912) {                // K fragments (refined), f16
        const int u = wid - 3456;           // u = g*12 + t
        const int g = u / 12, t = u % 12;
        const int key = g * 32 + l32;
        const int c0  = t * 16 + h * 8;
        hfrag hv;
        #pragma unroll
        for (int i = 0; i < 8; i++) {
            size_t idx = (size_t)(c0 + i) * NQ + key;
            hv[i] = (_Float16)refined[idx];
        }
        *(hfrag*)(void*)(KV + (size_t)g * 12288 + ((t * 64 + lane) * 8)) = hv;
    } else {                                // V fragments (latent*w4), bf16, permuted
        const int u = wid - 6912;           // u = g*12 + T*6 + cb
        const int g = u / 12, r = u % 12;
        const int T = r / 6, cb = r % 6;
        const int c  = cb * 32 + l32;
        const int k0 = g * 32 + T * 16 + 4 * h;
        bfrag bv;
        #pragma unroll
        for (int i = 0; i < 8; i++) {
            const int row = k0 + (i & 3) + 8 * (i >> 2);
            size_t idx = (size_t)c * NQ + row;
            bv[i] = f2bf(latent[idx] * w4[idx]);
        }
        *(bfrag*)(void*)(KV + (size_t)g * 12288 + 6144 + ((T * 6 + cb) * 64 + lane) * 8) = bv;
    }
}

// ---------------------------------------------------------------------------
// Flash: grid (72 q-tiles of 128, KS key-splits in 32-key units), 2 waves
// x 64 q, 72KB LDS/block -> 2 blocks/CU, 1 wave/SIMD.  Triple-buffered
// 24KB K|V tiles, staged 2 ahead; every fragment read feeds 2 MFMAs.
// ---------------------------------------------------------------------------
__device__ __forceinline__ void stage24(const short* KVsrc, char* dstb,
                                        int w, int lane) {
    // 24KB tile, 24 x 1KB chunks, 12 per wave
    const char* src = (const char*)KVsrc + w * 12288 + lane * 16;
    char* dst = dstb + w * 12288;           // wave-uniform base (+lane*16 HW)
    #pragma unroll
    for (int j = 0; j < 12; j++) gload_lds16(src + j * 1024, dst + j * 1024);
}

#define KLD(n)  *(const hfrag*)(const void*)(kb + (n) * 512 + lane * 8)
#define VLD(n)  *(const bfrag*)(const void*)(kb + 6144 + (n) * 512 + lane * 8)
#define QK2(kf, t) do { \
    S0 = __builtin_amdgcn_mfma_f32_32x32x16_f16((kf), qa[t], S0, 0, 0, 0); \
    S1 = __builtin_amdgcn_mfma_f32_32x32x16_f16((kf), qb[t], S1, 0, 0, 0); } while (0)
#define PV2(vf, cb, pA, pB) do { \
    OA[cb] = __builtin_amdgcn_mfma_f32_32x32x16_bf16((vf), (pA), OA[cb], 0, 0, 0); \
    OB[cb] = __builtin_amdgcn_mfma_f32_32x32x16_bf16((vf), (pB), OB[cb], 0, 0, 0); } while (0)
#define SGB __builtin_amdgcn_sched_group_barrier

__global__ __launch_bounds__(128, 1) void InterGate_flash(
    const short* __restrict__ Qf, const short* __restrict__ KV,
    short* __restrict__ Opart, float* __restrict__ l_ws, int KS)
{
    __shared__ __align__(16) short kv[3][12288];   // 3 x 24KB: K(f16) | V(bf16)

    const int tid  = threadIdx.x;
    const int lane = tid & 63, w = tid >> 6;       // w in {0,1}
    const int l32  = lane & 31, h = lane >> 5;
    const int qt   = blockIdx.x, ks = blockIdx.y;

    // key range in 32-key units (288 total)
    const int base = 288 / KS, rem = 288 % KS;
    const int start = ks * base + (ks < rem ? ks : rem);
    const int cnt   = base + (ks < rem ? 1 : 0);

    // two Q B-frag subtiles in registers (96 VGPR)
    const int qwA = qt * 4 + w * 2;
    hfrag qa[12], qb[12];
    #pragma unroll
    for (int t = 0; t < 12; t++) {
        qa[t] = *(const hfrag*)(const void*)(Qf + (((size_t)qwA * 12 + t) * 64 + lane) * 8);
        qb[t] = *(const hfrag*)(const void*)(Qf + (((size_t)(qwA + 1) * 12 + t) * 64 + lane) * 8);
    }

    facc16 OA[6], OB[6];
    #pragma unroll
    for (int cb = 0; cb < 6; cb++) {
        #pragma unroll
        for (int j = 0; j < 16; j++) { OA[cb][j] = 0.f; OB[cb][j] = 0.f; }
    }
    float lsA = 0.f, lsB = 0.f;

    // prologue: stage tiles 0 and 1 (12 loads each per wave)
    stage24(KV + (size_t)start * 12288,       (char*)&kv[0][0], w, lane);
    if (cnt > 1)
        stage24(KV + (size_t)(start + 1) * 12288, (char*)&kv[1][0], w, lane);

    const short* b0 = &kv[0][0];
    const short* b1 = &kv[1][0];
    const short* b2 = &kv[2][0];

    for (int kt = 0; kt < cnt; kt++) {
        // ---- tile boundary: counted wait (tile kt's batch landed) ----
        if (kt + 1 < cnt) { asm volatile("s_waitcnt vmcnt(12)" ::: "memory"); }
        else              { asm volatile("s_waitcnt vmcnt(0)" ::: "memory"); }
        __builtin_amdgcn_s_barrier();

        // stage tile kt+2 into b2 (its readers passed the previous barrier)
        if (kt + 2 < cnt)
            stage24(KV + (size_t)(start + kt + 2) * 12288, (char*)b2, w, lane);

        const short* kb = b0;

        // ---- QK: 12 K frags, each -> 2 MFMAs; -M0L folded into S init ----
        hfrag k0 = KLD(0), k1 = KLD(1), k2 = KLD(2), k3 = KLD(3);
        facc16 S0, S1;
        #pragma unroll
        for (int j = 0; j < 16; j++) { S0[j] = -M0L; S1[j] = -M0L; }
        __builtin_amdgcn_s_setprio(1);
        hfrag k4  = KLD(4);  QK2(k0, 0);
        hfrag k5  = KLD(5);  QK2(k1, 1);
        hfrag k6  = KLD(6);  QK2(k2, 2);
        hfrag k7  = KLD(7);  QK2(k3, 3);
        hfrag k8  = KLD(8);  QK2(k4, 4);
        hfrag k9  = KLD(9);  QK2(k5, 5);
        hfrag k10 = KLD(10); QK2(k6, 6);
        hfrag k11 = KLD(11); QK2(k7, 7);
        bfrag v0  = VLD(0);  QK2(k8, 8);
        bfrag v1  = VLD(1);  QK2(k9, 9);
        bfrag v2  = VLD(2);  QK2(k10, 10);
        bfrag v3  = VLD(3);  QK2(k11, 11);
        __builtin_amdgcn_s_setprio(0);
        // S layout: key = (j&3)+8*(j>>2)+4*h (lane-local), q = l32

        // ---- P = 2^S; tree-sum; pack (no cross-lane moves) ----
        float pA[16], pB[16];
        #pragma unroll
        for (int j = 0; j < 16; j++) {
            pA[j] = exp2_raw(S0[j]);
            pB[j] = exp2_raw(S1[j]);
        }
        lsA += (((pA[0]+pA[1])+(pA[2]+pA[3]))+((pA[4]+pA[5])+(pA[6]+pA[7])))
             + (((pA[8]+pA[9])+(pA[10]+pA[11]))+((pA[12]+pA[13])+(pA[14]+pA[15])));
        lsB += (((pB[0]+pB[1])+(pB[2]+pB[3]))+((pB[4]+pB[5])+(pB[6]+pB[7])))
             + (((pB[8]+pB[9])+(pB[10]+pB[11]))+((pB[12]+pB[13])+(pB[14]+pB[15])));
        int cpA[8], cpB[8];
        #pragma unroll
        for (int a = 0; a < 8; a++) {
            cpA[a] = cvtpk_bf16(pA[2 * a], pA[2 * a + 1]);
            cpB[a] = cvtpk_bf16(pB[2 * a], pB[2 * a + 1]);
        }
        bfrag pfA0 = __builtin_bit_cast(bfrag, (ifrag4){cpA[0], cpA[1], cpA[2], cpA[3]});
        bfrag pfA1 = __builtin_bit_cast(bfrag, (ifrag4){cpA[4], cpA[5], cpA[6], cpA[7]});
        bfrag pfB0 = __builtin_bit_cast(bfrag, (ifrag4){cpB[0], cpB[1], cpB[2], cpB[3]});
        bfrag pfB1 = __builtin_bit_cast(bfrag, (ifrag4){cpB[4], cpB[5], cpB[6], cpB[7]});

        // ---- PV: 12 V frags, each -> 2 MFMAs (V rows pre-permuted) ----
        __builtin_amdgcn_s_setprio(1);
        bfrag v4  = VLD(4);  PV2(v0, 0, pfA0, pfB0);
        bfrag v5  = VLD(5);  PV2(v1, 1, pfA0, pfB0);
        bfrag v6  = VLD(6);  PV2(v2, 2, pfA0, pfB0);
        bfrag v7  = VLD(7);  PV2(v3, 3, pfA0, pfB0);
        bfrag v8  = VLD(8);  PV2(v4, 4, pfA0, pfB0);
        bfrag v9  = VLD(9);  PV2(v5, 5, pfA0, pfB0);
        bfrag v10 = VLD(10); PV2(v6, 0, pfA1, pfB1);
        bfrag v11 = VLD(11); PV2(v7, 1, pfA1, pfB1);
        PV2(v8, 2, pfA1, pfB1);  PV2(v9, 3, pfA1, pfB1);
        PV2(v10, 4, pfA1, pfB1); PV2(v11, 5, pfA1, pfB1);
        __builtin_amdgcn_s_setprio(0);

        // ---- SGB pin: 4 reads; 12x{1 rd : 2 MFMA}; 8x{1 rd : 3 MFMA} ----
        SGB(0x100, 4, 0);
        #pragma unroll
        for (int i = 0; i < 12; i++) { SGB(0x100, 1, 0); SGB(0x8, 2, 0); }
        #pragma unroll
        for (int i = 0; i < 8; i++)  { SGB(0x100, 1, 0); SGB(0x8, 3, 0); }

        // rotate triple buffer (wave-uniform pointer swap)
        const short* tmp = b0; b0 = b1; b1 = b2; b2 = tmp;
    }

    // ---- epilogue: Opart[ks][q][c] (bf16, unnormalized) + l per query ----
    const int q0 = qt * 128 + w * 64 + l32;
    short* rowA = Opart + ((size_t)ks * NQ + q0) * NC;
    short* rowB = rowA + (size_t)32 * NC;
    #pragma unroll
    for (int cb = 0; cb < 6; cb++) {
        #pragma unroll
        for (int g = 0; g < 4; g++) {
            const int c0 = cb * 32 + 8 * g + 4 * h;
            sfrag4 sa, sb;
            #pragma unroll
            for (int r = 0; r < 4; r++) {
                sa[r] = f2bf(OA[cb][4 * g + r]);
                sb[r] = f2bf(OB[cb][4 * g + r]);
            }
            *(sfrag4*)(void*)(rowA + c0) = sa;
            *(sfrag4*)(void*)(rowB + c0) = sb;
        }
    }
    float la = lsA + __shfl_xor(lsA, 32);
    float lb = lsB + __shfl_xor(lsB, 32);
    if (h == 0) {
        l_ws[(size_t)ks * NQ + q0]      = la;
        l_ws[(size_t)ks * NQ + q0 + 32] = lb;
    }
}

// ---------------------------------------------------------------------------
// Combine: sum KS partials (common scale), normalize, transpose via LDS,
// fused epilogue out = refined*w5 + ctx.  288 blocks x 32 queries.
// ---------------------------------------------------------------------------
__global__ __launch_bounds__(256) void InterGate_combine(
    const short* __restrict__ Opart, const float* __restrict__ l_ws,
    const float* __restrict__ refined, const float* __restrict__ w5,
    float* __restrict__ out, int KS)
{
    __shared__ float ctx[32][193];
    __shared__ float sInv[32];
    const int qt = blockIdx.x, tid = threadIdx.x;

    if (tid < 32) {
        const int q = qt * 32 + tid;
        float L = 0.f;
        for (int ks = 0; ks < KS; ks++) L += l_ws[(size_t)ks * NQ + q];
        sInv[tid] = 1.f / L;
    }
    __syncthreads();

    for (int u = tid; u < 768; u += 256) {
        const int ql = u / 24, c0 = (u % 24) * 8;
        float acc[8] = {0.f, 0.f, 0.f, 0.f, 0.f, 0.f, 0.f, 0.f};
        for (int ks = 0; ks < KS; ks++) {
            bfrag pk = *(const bfrag*)(const void*)&Opart[((size_t)ks * NQ + qt * 32 + ql) * NC + c0];
            #pragma unroll
            for (int j = 0; j < 8; j++) acc[j] += bf2f(pk[j]);
        }
        const float inv = sInv[ql];
        #pragma unroll
        for (int j = 0; j < 8; j++) ctx[ql][c0 + j] = acc[j] * inv;
    }
    __syncthreads();

    for (int u = tid; u < 6144; u += 256) {
        const int c = u / 32, qx = u % 32;
        size_t o = (size_t)c * NQ + qt * 32 + qx;
        out[o] = refined[o] * w5[o] + ctx[qx][c];
    }
}

// ---------------------------------------------------------------------------
extern "C" void kernel_launch(void* const* d_in, const int* in_sizes, int n_in,
                              void* d_out, int out_size, void* d_ws, size_t ws_size,
                              hipStream_t stream)
{
    (void)in_sizes; (void)n_in; (void)out_size;
    const float* latent  = (const float*)d_in[0];
    const float* refined = (const float*)d_in[1];
    const float* w4      = (const float*)d_in[2];
    const float* w5      = (const float*)d_in[3];
    float* out = (float*)d_out;

    short* Qf = (short*)d_ws;
    short* KV = Qf + FR;                     // 2*FR shorts (K|V per 32-key group)
    const size_t basebytes = (size_t)3 * FR * 2;

    // KS=7 -> grid 504 (~2 blocks/CU, 72KB LDS each); fallbacks if ws small
    const int opts[4] = {7, 4, 2, 1};
    int KS = 0;
    for (int i = 0; i < 4; i++) {
        size_t need = basebytes + (size_t)opts[i] * ((size_t)NQ * NC * 2 + (size_t)NQ * 4);
        if (need <= ws_size) { KS = opts[i]; break; }
    }
    if (KS == 0) return;

    short* Opart = (short*)((char*)d_ws + basebytes);
    float* l_ws  = (float*)((char*)d_ws + basebytes + (size_t)KS * NQ * NC * 2);

    InterGate_prep<<<2592, 256, 0, stream>>>(latent, refined, w4, Qf, KV);
    dim3 fg(72, KS);
    InterGate_flash<<<fg, 128, 0, stream>>>(Qf, KV, Opart, l_ws, KS);
    InterGate_combine<<<288, 256, 0, stream>>>(Opart, l_ws, refined, w5, out, KS);
}

// Round 15
// 92.137 us; speedup vs baseline: 1.1079x; 1.1079x over previous
//
#include <hip/hip_runtime.h>
#include <stdint.h>

// InterGate: B=1, C=192, H=W=96.  Flash-attention formulation:
//   Q = (latent*w4)^T, K = refined^T, V = (latent*w4)^T   (all [9216, 192])
//   out = refined*w5 + (softmax(Q K^T) V)^T
// Round-15: r14 with the r13/r14 bug FIXED: key range is 144 64-key units
// (9216/64), not 72 -- r13/r14 attended only the first half of the keys,
// producing the identical deterministic absmax 5.97 in both.  All sync
// structure already audited correct:
//   * 8 waves x 32q (256 q/block), 64-key tiles (48KB), 2x48KB dbuf
//     (96KB -> 1 block/CU, 8 waves/CU), drain vmcnt(0) at tile boundaries
//   * 4 phases/tile: P1 K-g0->S0, P2 K-g1->S1, P3 sm(S0)+V-g0->PV,
//     P4 sm(S1)+V-g1->PV; ds_reads issued BEFORE each phase barrier;
//     PHASE_WAIT = s_barrier + lgkmcnt(0) + sched_barrier(0) (rule #18)
//   * f16 single-term swapped QK, no-max softmax (-M0L folded into S init),
//     permuted-V rows (P B-frag = cvt_pk words, zero cross-lane moves)

#define NQ 9216
#define NC 192
#define FR 1769472      // 9216*192 elements per fragment array
#define LOG2E 1.4426950408889634f
#define M0L 36.06737602f   // 25 * log2(e)

typedef short    bfrag  __attribute__((ext_vector_type(8)));   // 8 bf16
typedef _Float16 hfrag  __attribute__((ext_vector_type(8)));   // 8 f16
typedef short    sfrag4 __attribute__((ext_vector_type(4)));   // 4 bf16 (8B)
typedef float    facc16 __attribute__((ext_vector_type(16)));  // 32x32 accum
typedef int      ifrag4 __attribute__((ext_vector_type(4)));

__device__ __forceinline__ short f2bf(float x) {
    uint32_t u = __builtin_bit_cast(uint32_t, x);
    u = (u + 0x7fffu + ((u >> 16) & 1u)) >> 16;
    return (short)u;
}
__device__ __forceinline__ float bf2f(short s) {
    uint32_t u = ((uint32_t)(uint16_t)s) << 16;
    return __builtin_bit_cast(float, u);
}
__device__ __forceinline__ int cvtpk_bf16(float lo, float hi) {
    int r;
    asm("v_cvt_pk_bf16_f32 %0, %1, %2" : "=v"(r) : "v"(lo), "v"(hi));
    return r;
}
__device__ __forceinline__ float exp2_raw(float x) {   // 2^x via v_exp_f32
    float r;
    asm("v_exp_f32 %0, %1" : "=v"(r) : "v"(x));
    return r;
}
__device__ __forceinline__ void gload_lds16(const void* g, void* l) {
    __builtin_amdgcn_global_load_lds(
        (__attribute__((address_space(1))) const void*)(uintptr_t)g,
        (__attribute__((address_space(3))) void*)(uint32_t)(uintptr_t)l,
        16, 0, 0);
}

// ---------------------------------------------------------------------------
// Prep: fragment-ordered arrays for 32x32x16 (l32=lane&31, h=lane>>5).
// Qf (f16, B-frag, pre-scaled by log2e):
//   [qw(288)][t(12)][lane][i8] = log2e * Q[qw*32+l32][t*16+h*8+i]
// KV per 32-key group g (12288 shorts = 24KB), 288 groups:
//  [0]    K (f16, A-frag): [t(12)][lane][i8] = K[g*32+l32][t*16+h*8+i]
//  [6144] V (bf16, A-frag of V^T, PERMUTED key rows matching S' C/D order):
//         [T(2)][cb(6)][lane][i8] = V[g*32+T*16+(i&3)+8*(i>>2)+4*h][cb*32+l32]
// ---------------------------------------------------------------------------
__global__ __launch_bounds__(256) void InterGate_prep(
    const float* __restrict__ latent, const float* __restrict__ refined,
    const float* __restrict__ w4,
    short* __restrict__ Qf, short* __restrict__ KV)
{
    const int wid  = blockIdx.x * 4 + (threadIdx.x >> 6);
    const int lane = threadIdx.x & 63;
    const int l32  = lane & 31, h = lane >> 5;

    if (wid < 3456) {                       // Q fragments (latent*w4*log2e), f16
        const int qw = wid / 12, t = wid % 12;
        const int q  = qw * 32 + l32;
        const int c0 = t * 16 + h * 8;
        hfrag hv;
        #pragma unroll
        for (int i = 0; i < 8; i++) {
            size_t idx = (size_t)(c0 + i) * NQ + q;
            hv[i] = (_Float16)(latent[idx] * w4[idx] * LOG2E);
        }
        *(hfrag*)(void*)(Qf + ((size_t)wid * 64 + lane) * 8) = hv;
    } else if (wid < 6912) {                // K fragments (refined), f16
        const int u = wid - 3456;           // u = g*12 + t
        const int g = u / 12, t = u % 12;
        const int key = g * 32 + l32;
        const int c0  = t * 16 + h * 8;
        hfrag hv;
        #pragma unroll
        for (int i = 0; i < 8; i++) {
            size_t idx = (size_t)(c0 + i) * NQ + key;
            hv[i] = (_Float16)refined[idx];
        }
        *(hfrag*)(void*)(KV + (size_t)g * 12288 + ((t * 64 + lane) * 8)) = hv;
    } else {                                // V fragments (latent*w4), bf16, permuted
        const int u = wid - 6912;           // u = g*12 + T*6 + cb
        const int g = u / 12, r = u % 12;
        const int T = r / 6, cb = r % 6;
        const int c  = cb * 32 + l32;
        const int k0 = g * 32 + T * 16 + 4 * h;
        bfrag bv;
        #pragma unroll
        for (int i = 0; i < 8; i++) {
            const int row = k0 + (i & 3) + 8 * (i >> 2);
            size_t idx = (size_t)c * NQ + row;
            bv[i] = f2bf(latent[idx] * w4[idx]);
        }
        *(bfrag*)(void*)(KV + (size_t)g * 12288 + 6144 + ((T * 6 + cb) * 64 + lane) * 8) = bv;
    }
}

// ---------------------------------------------------------------------------
// Flash: grid (36 q-tiles of 256, KS key-splits in 64-key units, 144 total),
// 8 waves x 32 q.  64-key tiles = 48KB (2 consecutive 32-key groups),
// 2x48KB dbuf.  4 phases/tile; reads before phase barriers; drain vmcnt(0)
// at tile boundaries.
// ---------------------------------------------------------------------------
__device__ __forceinline__ void stage48(const short* KVsrc, char* dstb,
                                        int w, int lane) {
    // 48KB tile, 48 x 1KB chunks, 6 per wave
    const char* src = (const char*)KVsrc + w * 6144 + lane * 16;
    char* dst = dstb + w * 6144;            // wave-uniform base (+lane*16 HW)
    #pragma unroll
    for (int j = 0; j < 6; j++) gload_lds16(src + j * 1024, dst + j * 1024);
}

#define KLD(base, n)  *(const hfrag*)(const void*)(kb + (base) + (n) * 512 + lane * 8)
#define VLD(base, n)  *(const bfrag*)(const void*)(kb + (base) + (n) * 512 + lane * 8)
#define SOFTMAX(Sx, pf0, pf1) do {                                            \
    float p_[16];                                                             \
    _Pragma("unroll")                                                         \
    for (int j = 0; j < 16; j++) p_[j] = exp2_raw((Sx)[j]);                   \
    lsum += (((p_[0]+p_[1])+(p_[2]+p_[3]))+((p_[4]+p_[5])+(p_[6]+p_[7])))     \
          + (((p_[8]+p_[9])+(p_[10]+p_[11]))+((p_[12]+p_[13])+(p_[14]+p_[15])));\
    int cp_[8];                                                               \
    _Pragma("unroll")                                                         \
    for (int a = 0; a < 8; a++) cp_[a] = cvtpk_bf16(p_[2*a], p_[2*a+1]);      \
    pf0 = __builtin_bit_cast(bfrag, (ifrag4){cp_[0], cp_[1], cp_[2], cp_[3]});\
    pf1 = __builtin_bit_cast(bfrag, (ifrag4){cp_[4], cp_[5], cp_[6], cp_[7]});\
} while (0)
#define PHASE_WAIT do {                                                       \
    __builtin_amdgcn_s_barrier();                                             \
    asm volatile("s_waitcnt lgkmcnt(0)" ::: "memory");                        \
    __builtin_amdgcn_sched_barrier(0);                                        \
} while (0)
#define GLD2(jj) do { if (kt + 1 < cnt) {                                     \
    const char* s_ = (const char*)(KV + (size_t)(start + kt + 1) * 24576)     \
                     + w * 6144 + (jj) * 2048 + lane * 16;                    \
    char* d_ = (char*)b1 + w * 6144 + (jj) * 2048;                            \
    gload_lds16(s_, d_); gload_lds16(s_ + 1024, d_ + 1024);                   \
} } while (0)
#define QKM(Sx, kf, t) Sx = __builtin_amdgcn_mfma_f32_32x32x16_f16((kf), qf[t], Sx, 0, 0, 0)
#define PVM(vf, cb, pf) O[cb] = __builtin_amdgcn_mfma_f32_32x32x16_bf16((vf), (pf), O[cb], 0, 0, 0)

__global__ __launch_bounds__(512, 2) void InterGate_flash(
    const short* __restrict__ Qf, const short* __restrict__ KV,
    short* __restrict__ Opart, float* __restrict__ l_ws, int KS)
{
    __shared__ __align__(16) short kv[2][24576];   // 2 x 48KB (64-key tiles)

    const int tid  = threadIdx.x;
    const int lane = tid & 63, w = tid >> 6;       // 8 waves
    const int l32  = lane & 31, h = lane >> 5;
    const int qt   = blockIdx.x, ks = blockIdx.y;

    // key range in 64-key units (9216/64 = 144 total)  [r13/r14 bug: was 72]
    const int base = 144 / KS, rem = 144 % KS;
    const int start = ks * base + (ks < rem ? ks : rem);
    const int cnt   = base + (ks < rem ? 1 : 0);

    // Q B-frags in registers (48 VGPR)
    const int qw = qt * 8 + w;
    hfrag qf[12];
    #pragma unroll
    for (int t = 0; t < 12; t++)
        qf[t] = *(const hfrag*)(const void*)(Qf + (((size_t)qw * 12 + t) * 64 + lane) * 8);

    facc16 O[6];
    #pragma unroll
    for (int cb = 0; cb < 6; cb++)
        #pragma unroll
        for (int j = 0; j < 16; j++) O[cb][j] = 0.f;
    float lsum = 0.f;

    // prologue: stage tile 0
    stage48(KV + (size_t)start * 24576, (char*)&kv[0][0], w, lane);

    const short* b0 = &kv[0][0];
    const short* b1 = &kv[1][0];

    for (int kt = 0; kt < cnt; kt++) {
        // ---- tile boundary: drain staging queue, sync ----
        asm volatile("s_waitcnt vmcnt(0)" ::: "memory");
        __builtin_amdgcn_s_barrier();
        const short* kb = b0;

        // ================= P1: K g0 -> S0 =================
        hfrag k0 = KLD(0,0), k1 = KLD(0,1), k2 = KLD(0,2), k3 = KLD(0,3);
        hfrag k4 = KLD(0,4), k5 = KLD(0,5), k6 = KLD(0,6), k7 = KLD(0,7);
        GLD2(0);
        facc16 S0, S1;
        #pragma unroll
        for (int j = 0; j < 16; j++) { S0[j] = -M0L; S1[j] = -M0L; }
        PHASE_WAIT;
        __builtin_amdgcn_s_setprio(1);
        QKM(S0, k0, 0); QKM(S0, k1, 1); QKM(S0, k2, 2); QKM(S0, k3, 3);
        hfrag k8 = KLD(0,8), k9 = KLD(0,9), k10 = KLD(0,10), k11 = KLD(0,11);
        QKM(S0, k4, 4); QKM(S0, k5, 5); QKM(S0, k6, 6); QKM(S0, k7, 7);
        QKM(S0, k8, 8); QKM(S0, k9, 9); QKM(S0, k10, 10); QKM(S0, k11, 11);
        __builtin_amdgcn_s_setprio(0);
        // S layout: key = (j&3)+8*(j>>2)+4*h (lane-local), q = l32

        // ================= P2: K g1 -> S1 =================
        k0 = KLD(12288,0); k1 = KLD(12288,1); k2 = KLD(12288,2); k3 = KLD(12288,3);
        k4 = KLD(12288,4); k5 = KLD(12288,5); k6 = KLD(12288,6); k7 = KLD(12288,7);
        GLD2(1);
        PHASE_WAIT;
        __builtin_amdgcn_s_setprio(1);
        QKM(S1, k0, 0); QKM(S1, k1, 1); QKM(S1, k2, 2); QKM(S1, k3, 3);
        k8 = KLD(12288,8); k9 = KLD(12288,9); k10 = KLD(12288,10); k11 = KLD(12288,11);
        QKM(S1, k4, 4); QKM(S1, k5, 5); QKM(S1, k6, 6); QKM(S1, k7, 7);
        QKM(S1, k8, 8); QKM(S1, k9, 9); QKM(S1, k10, 10); QKM(S1, k11, 11);
        __builtin_amdgcn_s_setprio(0);

        // ========== P3: softmax(S0); V g0 -> PV ==========
        bfrag pf0, pf1;
        SOFTMAX(S0, pf0, pf1);
        bfrag v0 = VLD(6144,0), v1 = VLD(6144,1), v2 = VLD(6144,2), v3 = VLD(6144,3);
        bfrag v4 = VLD(6144,4), v5 = VLD(6144,5), v6 = VLD(6144,6), v7 = VLD(6144,7);
        GLD2(2);
        PHASE_WAIT;
        __builtin_amdgcn_s_setprio(1);
        PVM(v0, 0, pf0); PVM(v1, 1, pf0); PVM(v2, 2, pf0); PVM(v3, 3, pf0);
        bfrag v8 = VLD(6144,8), v9 = VLD(6144,9), v10 = VLD(6144,10), v11 = VLD(6144,11);
        PVM(v4, 4, pf0); PVM(v5, 5, pf0);
        PVM(v6, 0, pf1); PVM(v7, 1, pf1);
        PVM(v8, 2, pf1); PVM(v9, 3, pf1); PVM(v10, 4, pf1); PVM(v11, 5, pf1);
        __builtin_amdgcn_s_setprio(0);

        // ========== P4: softmax(S1); V g1 -> PV ==========
        SOFTMAX(S1, pf0, pf1);
        v0 = VLD(18432,0); v1 = VLD(18432,1); v2 = VLD(18432,2); v3 = VLD(18432,3);
        v4 = VLD(18432,4); v5 = VLD(18432,5); v6 = VLD(18432,6); v7 = VLD(18432,7);
        PHASE_WAIT;
        __builtin_amdgcn_s_setprio(1);
        PVM(v0, 0, pf0); PVM(v1, 1, pf0); PVM(v2, 2, pf0); PVM(v3, 3, pf0);
        v8 = VLD(18432,8); v9 = VLD(18432,9); v10 = VLD(18432,10); v11 = VLD(18432,11);
        PVM(v4, 4, pf0); PVM(v5, 5, pf0);
        PVM(v6, 0, pf1); PVM(v7, 1, pf1);
        PVM(v8, 2, pf1); PVM(v9, 3, pf1); PVM(v10, 4, pf1); PVM(v11, 5, pf1);
        __builtin_amdgcn_s_setprio(0);

        // swap double buffer (wave-uniform pointer swap)
        const short* tmp = b0; b0 = b1; b1 = tmp;
    }

    // ---- epilogue: Opart[ks][q][c] (bf16, unnormalized) + l per query ----
    const int q0 = qt * 256 + w * 32 + l32;
    short* row = Opart + ((size_t)ks * NQ + q0) * NC;
    #pragma unroll
    for (int cb = 0; cb < 6; cb++) {
        #pragma unroll
        for (int g = 0; g < 4; g++) {
            const int c0 = cb * 32 + 8 * g + 4 * h;
            sfrag4 s4;
            #pragma unroll
            for (int r = 0; r < 4; r++) s4[r] = f2bf(O[cb][4 * g + r]);
            *(sfrag4*)(void*)(row + c0) = s4;
        }
    }
    float lt = lsum + __shfl_xor(lsum, 32);
    if (h == 0) l_ws[(size_t)ks * NQ + q0] = lt;
}

// ---------------------------------------------------------------------------
// Combine: sum KS partials (common scale), normalize, transpose via LDS,
// fused epilogue out = refined*w5 + ctx.  288 blocks x 32 queries.
// ---------------------------------------------------------------------------
__global__ __launch_bounds__(256) void InterGate_combine(
    const short* __restrict__ Opart, const float* __restrict__ l_ws,
    const float* __restrict__ refined, const float* __restrict__ w5,
    float* __restrict__ out, int KS)
{
    __shared__ float ctx[32][193];
    __shared__ float sInv[32];
    const int qt = blockIdx.x, tid = threadIdx.x;

    if (tid < 32) {
        const int q = qt * 32 + tid;
        float L = 0.f;
        for (int ks = 0; ks < KS; ks++) L += l_ws[(size_t)ks * NQ + q];
        sInv[tid] = 1.f / L;
    }
    __syncthreads();

    for (int u = tid; u < 768; u += 256) {
        const int ql = u / 24, c0 = (u % 24) * 8;
        float acc[8] = {0.f, 0.f, 0.f, 0.f, 0.f, 0.f, 0.f, 0.f};
        for (int ks = 0; ks < KS; ks++) {
            bfrag pk = *(const bfrag*)(const void*)&Opart[((size_t)ks * NQ + qt * 32 + ql) * NC + c0];
            #pragma unroll
            for (int j = 0; j < 8; j++) acc[j] += bf2f(pk[j]);
        }
        const float inv = sInv[ql];
        #pragma unroll
        for (int j = 0; j < 8; j++) ctx[ql][c0 + j] = acc[j] * inv;
    }
    __syncthreads();

    for (int u = tid; u < 6144; u += 256) {
        const int c = u / 32, qx = u % 32;
        size_t o = (size_t)c * NQ + qt * 32 + qx;
        out[o] = refined[o] * w5[o] + ctx[qx][c];
    }
}

// ---------------------------------------------------------------------------
extern "C" void kernel_launch(void* const* d_in, const int* in_sizes, int n_in,
                              void* d_out, int out_size, void* d_ws, size_t ws_size,
                              hipStream_t stream)
{
    (void)in_sizes; (void)n_in; (void)out_size;
    const float* latent  = (const float*)d_in[0];
    const float* refined = (const float*)d_in[1];
    const float* w4      = (const float*)d_in[2];
    const float* w5      = (const float*)d_in[3];
    float* out = (float*)d_out;

    short* Qf = (short*)d_ws;
    short* KV = Qf + FR;                     // 2*FR shorts (K|V per 32-key group)
    const size_t basebytes = (size_t)3 * FR * 2;

    // KS=7 -> grid 252 (1 block/CU, 96KB LDS); fallbacks if ws small
    const int opts[4] = {7, 4, 2, 1};
    int KS = 0;
    for (int i = 0; i < 4; i++) {
        size_t need = basebytes + (size_t)opts[i] * ((size_t)NQ * NC * 2 + (size_t)NQ * 4);
        if (need <= ws_size) { KS = opts[i]; break; }
    }
    if (KS == 0) return;

    short* Opart = (short*)((char*)d_ws + basebytes);
    float* l_ws  = (float*)((char*)d_ws + basebytes + (size_t)KS * NQ * NC * 2);

    InterGate_prep<<<2592, 256, 0, stream>>>(latent, refined, w4, Qf, KV);
    dim3 fg(36, KS);
    InterGate_flash<<<fg, 512, 0, stream>>>(Qf, KV, Opart, l_ws, KS);
    InterGate_combine<<<288, 256, 0, stream>>>(Opart, l_ws, refined, w5, out, KS);
}